// Round 17
// baseline (143.575 us; speedup 1.0000x reference)
//
#include <hip/hip_runtime.h>

typedef __attribute__((ext_vector_type(8))) _Float16 f16x8;
typedef __attribute__((ext_vector_type(4))) float    f32x4;
typedef __attribute__((ext_vector_type(4))) int      i32x4;

#define IN_F   4096
#define OUT_F  4096
#define NGRP   32

#define GLOAD16(gsrc, ldst)                                                   \
    __builtin_amdgcn_global_load_lds(                                         \
        (const __attribute__((address_space(1))) unsigned int*)(gsrc),        \
        (__attribute__((address_space(3))) unsigned int*)(ldst), 16, 0, 0)

#define CFENCE  asm volatile("" ::: "memory")
#define BARRIER do { CFENCE; __builtin_amdgcn_s_barrier(); CFENCE; } while (0)
#define VMW4    asm volatile("s_waitcnt vmcnt(4)" ::: "memory")
#define VMW6    asm volatile("s_waitcnt vmcnt(6)" ::: "memory")

// ---------------- fused prepass: X fp32->f16 and int4 dequant->f16 ----------
__global__ __launch_bounds__(256)
void prep(const float* __restrict__ X, const int* __restrict__ QW,
          const float* __restrict__ S, _Float16* __restrict__ XF,
          _Float16* __restrict__ WF) {
    if (blockIdx.x < 8192) {
        size_t i = ((size_t)blockIdx.x * 256 + threadIdx.x) * 8;
        f32x4 a = *(const f32x4*)(X + i);
        f32x4 b = *(const f32x4*)(X + i + 4);
        f16x8 h;
        h[0] = (_Float16)a[0]; h[1] = (_Float16)a[1];
        h[2] = (_Float16)a[2]; h[3] = (_Float16)a[3];
        h[4] = (_Float16)b[0]; h[5] = (_Float16)b[1];
        h[6] = (_Float16)b[2]; h[7] = (_Float16)b[3];
        *(f16x8*)(XF + i) = h;
    } else {
        size_t t  = ((size_t)blockIdx.x - 8192) * 256 + threadIdx.x;
        size_t jj = t * 4;                   // int32 index; 2048 per row
        size_t o  = jj >> 11;
        size_t jr = jj & 2047;
        const float s = S[o * NGRP + (jr >> 6)];   // group const across 4 int32
        i32x4 q = *(const i32x4*)(QW + jj);
        f16x8 h;
#pragma unroll
        for (int j = 0; j < 4; ++j) {
            const int v = q[j];
            h[2 * j]     = (_Float16)((float)(((v >> 4) & 15) - 8) * s);
            h[2 * j + 1] = (_Float16)((float)((v & 15) - 8) * s);
        }
        *(f16x8*)(WF + jj * 2) = h;
    }
}

// --- main GEMM: 256^2, BK=32, 3-slot ring, full-tile lead, ROTATION swizzle -
// r13 chassis with its conflict bug fixed. Per tile t: {12 frag b128 reads
// (slot t%3) | stage t+2 -> slot (t+2)%3 | 32 MFMA} ; VMW4 ; BARRIER.
// Rotation swizzle: source chunk ks (16B) of row r lives at slot
// (ks+(r>>1))&3 of the row's 64B line. Bank check (lanes 0-7, ks=0):
// banks {0-3},{16-19},{4-7},{20-23},{8-11},{24-27},{12-15},{28-31} -- every
// 8-lane window covers all 32 banks once -> conflict-free (r13's (row&3)<<4
// XOR collided rows i,i+4 4-way -> its 1.26e7 conflicts). (r+128)>>1 == r>>1
// (mod 4), so both DMA row-halves share one source column.
// Ledger: VMW4 at tile end retires t+1 (issued one FULL tile ~1200cyc ago --
// vs r10's ~550cyc 1-phase lead), keeps t+2 (4 loads); barrier publishes.
// WAR: slot (t+2)%3 last read at t-1, >=1 barrier before the stage.
__global__ __launch_bounds__(512, 2)
void gemm_rr(const _Float16* __restrict__ A,
             const _Float16* __restrict__ B,
             float*          __restrict__ C)
{
    extern __shared__ char LDSc[];      // 3 slots x 32 KB (A 16K + B 16K)

    const int tid  = threadIdx.x;
    const int lane = tid & 63;
    const int wid  = tid >> 6;
    const int wm   = wid >> 2;          // 0..1 -> M half (128 rows)
    const int wn   = wid & 3;           // 0..3 -> N quarter (64 cols)

    const int bid = blockIdx.x;         // 256 blocks, %8==0
    const int swz = (bid & 7) * 32 + (bid >> 3);
    const int bm0 = (swz >> 4) * 256;
    const int bn0 = (swz & 15) * 256;

    // staging: thread -> rows tr, tr+128; dest slot (tid&3); source chunk
    // ks_src = ((tid&3) - (tr>>1)) & 3  (rotation; same for row tr+128)
    const int tr  = tid >> 2;                                   // 0..127
    const int kss = ((tid & 3) + 4 - ((tr >> 1) & 3)) & 3;
    const _Float16* Asrc = A + (size_t)(bm0 + tr) * IN_F + kss * 8;
    const _Float16* Bsrc = B + (size_t)(bn0 + tr) * IN_F + kss * 8;
    const int dstoff = wid * 1024;                              // wave-uniform

    // frag-read byte offsets: row*64 + ((ks + (row>>1))&3)*16, ks = lane>>4
    const int lane15 = lane & 15;
    const int ks     = lane >> 4;
    int aoff[8], boff[4];
#pragma unroll
    for (int m = 0; m < 8; ++m) {
        const int ar = wm * 128 + m * 16 + lane15;
        aoff[m] = ar * 64 + (((ks + (ar >> 1)) & 3) << 4);
    }
#pragma unroll
    for (int n = 0; n < 4; ++n) {
        const int br = wn * 64 + n * 16 + lane15;
        boff[n] = br * 64 + (((ks + (br >> 1)) & 3) << 4);
    }

    f16x8 a[8], b[4];
    f32x4 acc[8][4];
#pragma unroll
    for (int m = 0; m < 8; ++m)
#pragma unroll
        for (int n = 0; n < 4; ++n) acc[m][n] = (f32x4)0.0f;

#define STAGE(KT, SL) do {                                                    \
        char* d_ = LDSc + (SL) * 32768 + dstoff;                              \
        GLOAD16(Asrc + (KT) * 32, d_);                                        \
        GLOAD16(Asrc + (size_t)128 * IN_F + (KT) * 32, d_ + 8192);            \
        GLOAD16(Bsrc + (KT) * 32, d_ + 16384);                                \
        GLOAD16(Bsrc + (size_t)128 * IN_F + (KT) * 32, d_ + 24576); } while (0)

    // prologue: tiles 0,1 -> slots 0,1; VMW4 retires tile0, keeps tile1
    STAGE(0, 0); STAGE(1, 1);
    VMW4; BARRIER;

    int sl = 0;                         // t % 3
    for (int t = 0; t < 128; ++t) {
        const int s2 = (sl >= 1) ? sl - 1 : 2;     // (t+2) % 3
        char* base = LDSc + sl * 32768;
#pragma unroll
        for (int m = 0; m < 8; ++m) a[m] = *(const f16x8*)(base + aoff[m]);
#pragma unroll
        for (int n = 0; n < 4; ++n) b[n] = *(const f16x8*)(base + 16384 + boff[n]);
        STAGE((t + 2) & 127, s2);       // t>=126: dead restage, uniform counts
        __builtin_amdgcn_s_setprio(1);
#pragma unroll
        for (int m = 0; m < 8; ++m)
#pragma unroll
            for (int n = 0; n < 4; ++n)
                acc[m][n] = __builtin_amdgcn_mfma_f32_16x16x32_f16(
                    a[m], b[n], acc[m][n], 0, 0, 0);
        __builtin_amdgcn_s_setprio(0);
        VMW4; BARRIER;                  // retire t+1 (full-tile lead), publish
        sl = (sl == 2) ? 0 : sl + 1;
    }
    asm volatile("s_waitcnt vmcnt(0)" ::: "memory");   // drain dead stages

#pragma unroll
    for (int m = 0; m < 8; ++m) {
        const int Mr = bm0 + wm * 128 + m * 16 + ks * 4;
#pragma unroll
        for (int n = 0; n < 4; ++n) {
            const int Nc = bn0 + wn * 64 + n * 16 + lane15;
#pragma unroll
            for (int r = 0; r < 4; ++r)
                C[(size_t)(Mr + r) * OUT_F + Nc] = acc[m][n][r];
        }
    }
#undef STAGE
}

// ---------------- fallback: champion round-10 merged-phase 256^2 ------------
__global__ __launch_bounds__(512, 2)
void gemm8p(const _Float16* __restrict__ A,
            const _Float16* __restrict__ B,
            float*          __restrict__ C)
{
    extern __shared__ char LDSc[];
    char* const ldsA = LDSc;
    char* const ldsB = LDSc + 65536;

    const int tid  = threadIdx.x;
    const int lane = tid & 63;
    const int wid  = tid >> 6;
    const int wm   = wid >> 2;
    const int wn   = wid & 3;

    const int bid = blockIdx.x;
    const int swz = (bid & 7) * 32 + (bid >> 3);
    const int bm0 = (swz >> 4) * 256;
    const int bn0 = (swz & 15) * 256;

    const int r0 = tid >> 3;
    const int cs = ((tid & 7) * 16) ^ ((r0 & 7) << 4);
    const _Float16* Asrc = A + (size_t)(bm0 + r0) * IN_F + (cs >> 1);
    const _Float16* Bsrc = B + (size_t)(bn0 + r0) * IN_F + (cs >> 1);
    const int dstoff = wid * 1024;

    const int lane15 = lane & 15;
    const int swr = (lane & 7) << 4;
    const int c0 = ((lane >> 4) * 16) ^ swr;
    const int c1 = (64 + (lane >> 4) * 16) ^ swr;
    int rAoff[4], rBoff[2];
#pragma unroll
    for (int mm = 0; mm < 4; ++mm) rAoff[mm] = (wm * 64 + mm * 16 + lane15) * 128;
#pragma unroll
    for (int nn = 0; nn < 2; ++nn) rBoff[nn] = (wn * 32 + nn * 16 + lane15) * 128;

    f16x8 afr[4][2], blo[2][2], bhi[2][2];
    f32x4 acc[8][4];
#pragma unroll
    for (int m = 0; m < 8; ++m)
#pragma unroll
        for (int n = 0; n < 4; ++n) acc[m][n] = (f32x4)0.0f;

#define STAGE_A(HALF, KT, BUF) do {                                           \
        const _Float16* s_ = Asrc + (size_t)(HALF) * 128 * IN_F + (KT) * 64;  \
        char* d_ = ldsA + ((BUF) * 2 + (HALF)) * 16384 + dstoff;              \
        GLOAD16(s_, d_);                                                      \
        GLOAD16(s_ + (size_t)64 * IN_F, d_ + 8192); } while (0)

#define STAGE_B(HALF, KT, BUF) do {                                           \
        const _Float16* s_ = Bsrc + (size_t)(HALF) * 128 * IN_F + (KT) * 64;  \
        char* d_ = ldsB + ((BUF) * 2 + (HALF)) * 16384 + dstoff;              \
        GLOAD16(s_, d_);                                                      \
        GLOAD16(s_ + (size_t)64 * IN_F, d_ + 8192); } while (0)

#define RD_A(BUF, QM) do { char* ab_ = ldsA + ((BUF) * 2 + (QM)) * 16384;     \
        _Pragma("unroll") for (int mm = 0; mm < 4; ++mm) {                    \
            afr[mm][0] = *(const f16x8*)(ab_ + rAoff[mm] + c0);               \
            afr[mm][1] = *(const f16x8*)(ab_ + rAoff[mm] + c1); } } while (0)

#define RD_B(BUF, QN, DST) do { char* bb_ = ldsB + ((BUF) * 2 + (QN)) * 16384;\
        _Pragma("unroll") for (int nn = 0; nn < 2; ++nn) {                    \
            DST[nn][0] = *(const f16x8*)(bb_ + rBoff[nn] + c0);               \
            DST[nn][1] = *(const f16x8*)(bb_ + rBoff[nn] + c1); } } while (0)

#define MFMA_Q(QM, QN, BQ)                                                    \
        __builtin_amdgcn_s_setprio(1);                                        \
        _Pragma("unroll") for (int mm = 0; mm < 4; ++mm)                      \
        _Pragma("unroll") for (int nn = 0; nn < 2; ++nn)                      \
        _Pragma("unroll") for (int kk = 0; kk < 2; ++kk)                      \
            acc[(QM)*4+mm][(QN)*2+nn] =                                       \
                __builtin_amdgcn_mfma_f32_16x16x32_f16(                       \
                    afr[mm][kk], BQ[nn][kk], acc[(QM)*4+mm][(QN)*2+nn],0,0,0);\
        __builtin_amdgcn_s_setprio(0);

    STAGE_A(0, 0, 0); STAGE_B(0, 0, 0); STAGE_B(1, 0, 0); STAGE_A(1, 0, 0);
    STAGE_A(0, 1, 1); STAGE_B(0, 1, 1); STAGE_B(1, 1, 1);
    VMW6; BARRIER;

    for (int t = 0; t < 64; t += 2) {
        const int k2 = (t + 2) & 63;
        const int k3 = (t + 3) & 63;
        RD_A(0, 0); RD_B(0, 0, blo); RD_B(0, 1, bhi);
        STAGE_A(1, t + 1, 1);
        MFMA_Q(0, 0, blo); MFMA_Q(0, 1, bhi);
        BARRIER;
        RD_A(0, 1);
        STAGE_A(0, k2, 0); STAGE_B(0, k2, 0); STAGE_B(1, k2, 0);
        MFMA_Q(1, 0, blo); MFMA_Q(1, 1, bhi);
        VMW6; BARRIER;
        RD_A(1, 0); RD_B(1, 0, blo); RD_B(1, 1, bhi);
        STAGE_A(1, k2, 0);
        MFMA_Q(0, 0, blo); MFMA_Q(0, 1, bhi);
        BARRIER;
        RD_A(1, 1);
        STAGE_A(0, k3, 1); STAGE_B(0, k3, 1); STAGE_B(1, k3, 1);
        MFMA_Q(1, 0, blo); MFMA_Q(1, 1, bhi);
        VMW6; BARRIER;
    }
    asm volatile("s_waitcnt vmcnt(0)" ::: "memory");

#pragma unroll
    for (int m = 0; m < 8; ++m) {
        const int Mr = bm0 + (m >> 2) * 128 + wm * 64 + (m & 3) * 16 + (lane >> 4) * 4;
#pragma unroll
        for (int n = 0; n < 4; ++n) {
            const int Nc = bn0 + (n >> 1) * 128 + wn * 32 + (n & 1) * 16 + lane15;
#pragma unroll
            for (int r = 0; r < 4; ++r)
                C[(size_t)(Mr + r) * OUT_F + Nc] = acc[m][n][r];
        }
    }
#undef STAGE_A
#undef STAGE_B
#undef RD_A
#undef RD_B
#undef MFMA_Q
}

extern "C" void kernel_launch(void* const* d_in, const int* in_sizes, int n_in,
                              void* d_out, int out_size, void* d_ws, size_t ws_size,
                              hipStream_t stream) {
    (void)in_sizes; (void)n_in; (void)out_size; (void)ws_size;
    const float* x  = (const float*)d_in[0];
    const int*   qw = (const int*)d_in[1];
    const float* s  = (const float*)d_in[2];
    float*       out = (float*)d_out;

    _Float16* xf = (_Float16*)d_ws;
    _Float16* wf = xf + (size_t)OUT_F * IN_F;
    prep<<<dim3(16384), dim3(256), 0, stream>>>(x, qw, s, xf, wf);

    hipError_t e1 = hipFuncSetAttribute((const void*)gemm_rr,
        hipFuncAttributeMaxDynamicSharedMemorySize, 98304);
    if (e1 == hipSuccess) {
        gemm_rr<<<dim3(256), dim3(512), 98304, stream>>>(xf, wf, out);
        return;
    }
    hipError_t e2 = hipFuncSetAttribute((const void*)gemm8p,
        hipFuncAttributeMaxDynamicSharedMemorySize, 131072);
    if (e2 == hipSuccess)
        gemm8p<<<dim3(256), dim3(512), 131072, stream>>>(xf, wf, out);
}

// Round 18
// 134.714 us; speedup vs baseline: 1.0658x; 1.0658x over previous
//
#include <hip/hip_runtime.h>

typedef __attribute__((ext_vector_type(8))) _Float16 f16x8;
typedef __attribute__((ext_vector_type(4))) float    f32x4;
typedef __attribute__((ext_vector_type(4))) int      i32x4;

#define IN_F   4096
#define OUT_F  4096
#define NGRP   32
#define NKT    64          /* K-tiles of 64 */

#define GLOAD16(gsrc, ldst)                                                   \
    __builtin_amdgcn_global_load_lds(                                         \
        (const __attribute__((address_space(1))) unsigned int*)(gsrc),        \
        (__attribute__((address_space(3))) unsigned int*)(ldst), 16, 0, 0)

#define CFENCE  asm volatile("" ::: "memory")
#define BARRIER do { CFENCE; __builtin_amdgcn_s_barrier(); CFENCE; } while (0)
#define VMW6    asm volatile("s_waitcnt vmcnt(6)" ::: "memory")

// ---------------- fused prepass: X fp32->f16 and int4 dequant->f16 ----------
__global__ __launch_bounds__(256)
void prep(const float* __restrict__ X, const int* __restrict__ QW,
          const float* __restrict__ S, _Float16* __restrict__ XF,
          _Float16* __restrict__ WF) {
    if (blockIdx.x < 8192) {
        size_t i = ((size_t)blockIdx.x * 256 + threadIdx.x) * 8;
        f32x4 a = *(const f32x4*)(X + i);
        f32x4 b = *(const f32x4*)(X + i + 4);
        f16x8 h;
        h[0] = (_Float16)a[0]; h[1] = (_Float16)a[1];
        h[2] = (_Float16)a[2]; h[3] = (_Float16)a[3];
        h[4] = (_Float16)b[0]; h[5] = (_Float16)b[1];
        h[6] = (_Float16)b[2]; h[7] = (_Float16)b[3];
        *(f16x8*)(XF + i) = h;
    } else {
        size_t t  = ((size_t)blockIdx.x - 8192) * 256 + threadIdx.x;
        size_t jj = t * 4;                   // int32 index; 2048 per row
        size_t o  = jj >> 11;
        size_t jr = jj & 2047;
        const float s = S[o * NGRP + (jr >> 6)];   // group const across 4 int32
        i32x4 q = *(const i32x4*)(QW + jj);
        f16x8 h;
#pragma unroll
        for (int j = 0; j < 4; ++j) {
            const int v = q[j];
            h[2 * j]     = (_Float16)((float)(((v >> 4) & 15) - 8) * s);
            h[2 * j + 1] = (_Float16)((float)((v & 15) - 8) * s);
        }
        *(f16x8*)(WF + jj * 2) = h;
    }
}

// ---------------- main GEMM: 256^2, BK=64, MERGED phases (2/K-tile) ---------
// FINAL champion (rounds 10/14/16): GEMM 116.6-118.8us, MfmaUtil 51.4-52.6%,
// 0 bank conflicts, total ~135us (= 2.4x round-1 baseline). Per K-tile, 2
// phases of 2 quadrants (32 MFMA) each; 4 barriers per 2 K-tiles. T2 swizzle
// byte^=(row&7)<<4 realized as pre-swizzled global source (linear DMA dest)
// + swizzled ds_read (rule #21; 128B rows -> every 8-lane window covers all
// 32 banks -> fully conflict-free).
// Stage plan: PA: A1(t+1)->b1. PB: A0,B0,B1(t+2)->b0. PC: A1(t+2)->b0.
// PD: A0,B0,B1(t+3)->b1. Every stage >=1 barrier after its region's last
// read. VMW6 at PB/PD ends retires exactly the next buffer's 4 stages
// (8 loads), keeps newest 3 stages (6 loads) in flight; the trailing
// barrier publishes all waves' DMA landings before the reads.
// Refuted alternatives (all refcheck'd, all slower): 2-bar/phase 49%,
// 1-bar 8-phase 51.3%, read-ahead (pinned 46% / clean 48.2%), 32x32 MFMA
// 46% (+conflicts), A-direct-global 17.5%, 2-block TLP reshape 23.7%,
// BK=32 ring (XOR 46.6% conflicted / rotation 51% conflict-free).
__global__ __launch_bounds__(512, 2)
void gemm8p(const _Float16* __restrict__ A,
            const _Float16* __restrict__ B,
            float*          __restrict__ C)
{
    extern __shared__ char LDSc[];
    char* const ldsA = LDSc;
    char* const ldsB = LDSc + 65536;

    const int tid  = threadIdx.x;
    const int lane = tid & 63;
    const int wid  = tid >> 6;
    const int wm   = wid >> 2;          // 0..1
    const int wn   = wid & 3;           // 0..3

    const int bid = blockIdx.x;         // 256 blocks (16x16 tiles), %8==0
    const int swz = (bid & 7) * 32 + (bid >> 3);
    const int bm0 = (swz >> 4) * 256;
    const int bn0 = (swz & 15) * 256;

    // staging source: thread covers rows r0 and r0+64 of a half-tile,
    // 16 B at swizzled byte-col cs (involution: src-perm == read-perm)
    const int r0 = tid >> 3;                                // 0..63
    const int cs = ((tid & 7) * 16) ^ ((r0 & 7) << 4);      // 0..127
    const _Float16* Asrc = A + (size_t)(bm0 + r0) * IN_F + (cs >> 1);
    const _Float16* Bsrc = B + (size_t)(bn0 + r0) * IN_F + (cs >> 1);
    const int dstoff = wid * 1024;                          // wave-uniform

    // frag-read offsets (swizzled)
    const int lane15 = lane & 15;
    const int swr = (lane & 7) << 4;
    const int c0 = ((lane >> 4) * 16) ^ swr;        // kk=0 byte col
    const int c1 = (64 + (lane >> 4) * 16) ^ swr;   // kk=1
    int rAoff[4], rBoff[2];
#pragma unroll
    for (int mm = 0; mm < 4; ++mm) rAoff[mm] = (wm * 64 + mm * 16 + lane15) * 128;
#pragma unroll
    for (int nn = 0; nn < 2; ++nn) rBoff[nn] = (wn * 32 + nn * 16 + lane15) * 128;

    f16x8 afr[4][2], blo[2][2], bhi[2][2];
    f32x4 acc[8][4];
#pragma unroll
    for (int m = 0; m < 8; ++m)
#pragma unroll
        for (int n = 0; n < 4; ++n) acc[m][n] = (f32x4)0.0f;

#define STAGE_A(HALF, KT, BUF) do {                                           \
        const _Float16* s_ = Asrc + (size_t)(HALF) * 128 * IN_F + (KT) * 64;  \
        char* d_ = ldsA + ((BUF) * 2 + (HALF)) * 16384 + dstoff;              \
        GLOAD16(s_, d_);                                                      \
        GLOAD16(s_ + (size_t)64 * IN_F, d_ + 8192); } while (0)

#define STAGE_B(HALF, KT, BUF) do {                                           \
        const _Float16* s_ = Bsrc + (size_t)(HALF) * 128 * IN_F + (KT) * 64;  \
        char* d_ = ldsB + ((BUF) * 2 + (HALF)) * 16384 + dstoff;              \
        GLOAD16(s_, d_);                                                      \
        GLOAD16(s_ + (size_t)64 * IN_F, d_ + 8192); } while (0)

#define RD_A(BUF, QM) do { char* ab_ = ldsA + ((BUF) * 2 + (QM)) * 16384;     \
        _Pragma("unroll") for (int mm = 0; mm < 4; ++mm) {                    \
            afr[mm][0] = *(const f16x8*)(ab_ + rAoff[mm] + c0);               \
            afr[mm][1] = *(const f16x8*)(ab_ + rAoff[mm] + c1); } } while (0)

#define RD_B(BUF, QN, DST) do { char* bb_ = ldsB + ((BUF) * 2 + (QN)) * 16384;\
        _Pragma("unroll") for (int nn = 0; nn < 2; ++nn) {                    \
            DST[nn][0] = *(const f16x8*)(bb_ + rBoff[nn] + c0);               \
            DST[nn][1] = *(const f16x8*)(bb_ + rBoff[nn] + c1); } } while (0)

#define MFMA_Q(QM, QN, BQ)                                                    \
        __builtin_amdgcn_s_setprio(1);                                        \
        _Pragma("unroll") for (int mm = 0; mm < 4; ++mm)                      \
        _Pragma("unroll") for (int nn = 0; nn < 2; ++nn)                      \
        _Pragma("unroll") for (int kk = 0; kk < 2; ++kk)                      \
            acc[(QM)*4+mm][(QN)*2+nn] =                                       \
                __builtin_amdgcn_mfma_f32_16x16x32_f16(                       \
                    afr[mm][kk], BQ[nn][kk], acc[(QM)*4+mm][(QN)*2+nn],0,0,0);\
        __builtin_amdgcn_s_setprio(0);

    // prologue: K0 full -> buf0, K1 {A0,B0,B1} -> buf1 (7 stages, 14 loads).
    STAGE_A(0, 0, 0); STAGE_B(0, 0, 0); STAGE_B(1, 0, 0); STAGE_A(1, 0, 0);
    STAGE_A(0, 1, 1); STAGE_B(0, 1, 1); STAGE_B(1, 1, 1);
    VMW6; BARRIER;

    for (int t = 0; t < NKT; t += 2) {
        const int k2 = (t + 2) & 63;   // t=62 -> dead restage of K0/K1
        const int k3 = (t + 3) & 63;
        // ---- PA: quadrants Q00,Q01 of K-tile t (buf0) ----
        RD_A(0, 0); RD_B(0, 0, blo); RD_B(0, 1, bhi);
        STAGE_A(1, t + 1, 1);
        MFMA_Q(0, 0, blo); MFMA_Q(0, 1, bhi);
        BARRIER;
        // ---- PB: quadrants Q10,Q11 (buf0) ; stage t+2 A0/B0/B1 -> b0 ----
        RD_A(0, 1);
        STAGE_A(0, k2, 0); STAGE_B(0, k2, 0); STAGE_B(1, k2, 0);
        MFMA_Q(1, 0, blo); MFMA_Q(1, 1, bhi);
        VMW6; BARRIER;      // retires buf1 K-tile t+1; barrier publishes
        // ---- PC: quadrants Q00,Q01 of K-tile t+1 (buf1) ----
        RD_A(1, 0); RD_B(1, 0, blo); RD_B(1, 1, bhi);
        STAGE_A(1, k2, 0);
        MFMA_Q(0, 0, blo); MFMA_Q(0, 1, bhi);
        BARRIER;
        // ---- PD: quadrants Q10,Q11 (buf1) ; stage t+3 A0/B0/B1 -> b1 ----
        RD_A(1, 1);
        STAGE_A(0, k3, 1); STAGE_B(0, k3, 1); STAGE_B(1, k3, 1);
        MFMA_Q(1, 0, blo); MFMA_Q(1, 1, bhi);
        VMW6; BARRIER;      // retires buf0 K-tile t+2
    }
    asm volatile("s_waitcnt vmcnt(0)" ::: "memory");   // drain DMA before end

#pragma unroll
    for (int m = 0; m < 8; ++m) {
        const int Mr = bm0 + (m >> 2) * 128 + wm * 64 + (m & 3) * 16 + (lane >> 4) * 4;
#pragma unroll
        for (int n = 0; n < 4; ++n) {
            const int Nc = bn0 + (n >> 1) * 128 + wn * 32 + (n & 1) * 16 + lane15;
#pragma unroll
            for (int r = 0; r < 4; ++r)
                C[(size_t)(Mr + r) * OUT_F + Nc] = acc[m][n][r];
        }
    }
#undef STAGE_A
#undef STAGE_B
#undef RD_A
#undef RD_B
#undef MFMA_Q
}

// ---------------- fallback: m97-structure GEMM (static 16 KB LDS) ----------
__global__ __launch_bounds__(256, 3)
void gemm_f16(const _Float16* __restrict__ A,
              const _Float16* __restrict__ B,
              float*          __restrict__ C)
{
    __shared__ __align__(16) _Float16 lA[128 * 32];
    __shared__ __align__(16) _Float16 lB[128 * 32];

    const int tid  = threadIdx.x;
    const int lane = tid & 63;
    const int bid = blockIdx.x;
    const int swz = (bid & 7) * 128 + (bid >> 3);
    const int bm0 = (swz >> 5) * 128;
    const int bn0 = (swz & 31) * 128;

    const int sr = tid >> 2;
    const int sc = (tid & 3) * 8;
    const _Float16* Aps = A + (size_t)(bm0 + sr) * IN_F + sc;
    const _Float16* Bps = B + (size_t)(bn0 + sr) * IN_F + sc;
    char* lAb = (char*)lA + (tid & ~63) * 16;
    char* lBb = (char*)lB + (tid & ~63) * 16;

    const int wv = tid >> 6;
    const int wr = (wv >> 1) * 64;
    const int wc = (wv & 1)  * 64;
    const int lr  = lane & 15;
    const int lkb = (lane >> 4) * 16;

    f32x4 acc[4][4];
#pragma unroll
    for (int m = 0; m < 4; ++m)
#pragma unroll
        for (int n = 0; n < 4; ++n) acc[m][n] = (f32x4)0.0f;

    for (int kt = 0; kt < 128; ++kt) {
        __syncthreads();
        {
            const _Float16* ak = Aps + kt * 32;
            const _Float16* bk = Bps + kt * 32;
            GLOAD16(ak, lAb);
            GLOAD16(ak + (size_t)64 * IN_F, lAb + 4096);
            GLOAD16(bk, lBb);
            GLOAD16(bk + (size_t)64 * IN_F, lBb + 4096);
        }
        __syncthreads();

        f16x8 a[4], b[4];
#pragma unroll
        for (int m = 0; m < 4; ++m)
            a[m] = *(const f16x8*)((const char*)lA + (wr + m * 16 + lr) * 64 + lkb);
#pragma unroll
        for (int n = 0; n < 4; ++n)
            b[n] = *(const f16x8*)((const char*)lB + (wc + n * 16 + lr) * 64 + lkb);
#pragma unroll
        for (int m = 0; m < 4; ++m)
#pragma unroll
            for (int n = 0; n < 4; ++n)
                acc[m][n] = __builtin_amdgcn_mfma_f32_16x16x32_f16(
                    a[m], b[n], acc[m][n], 0, 0, 0);
    }

    const int crow = bm0 + wr + (lane >> 4) * 4;
    const int ccol = bn0 + wc + lr;
#pragma unroll
    for (int m = 0; m < 4; ++m)
#pragma unroll
        for (int n = 0; n < 4; ++n)
#pragma unroll
            for (int r = 0; r < 4; ++r)
                C[(size_t)(crow + m * 16 + r) * OUT_F + (ccol + n * 16)]
                    = acc[m][n][r];
}

extern "C" void kernel_launch(void* const* d_in, const int* in_sizes, int n_in,
                              void* d_out, int out_size, void* d_ws, size_t ws_size,
                              hipStream_t stream) {
    (void)in_sizes; (void)n_in; (void)out_size; (void)ws_size;
    const float* x  = (const float*)d_in[0];
    const int*   qw = (const int*)d_in[1];
    const float* s  = (const float*)d_in[2];
    float*       out = (float*)d_out;

    _Float16* xf = (_Float16*)d_ws;
    _Float16* wf = xf + (size_t)OUT_F * IN_F;
    prep<<<dim3(16384), dim3(256), 0, stream>>>(x, qw, s, xf, wf);

    hipError_t e = hipFuncSetAttribute((const void*)gemm8p,
        hipFuncAttributeMaxDynamicSharedMemorySize, 131072);
    if (e == hipSuccess)
        gemm8p<<<dim3(256), dim3(512), 131072, stream>>>(xf, wf, out);
    else
        gemm_f16<<<dim3(1024), dim3(256), 0, stream>>>(xf, wf, out);
}